// Round 1
// baseline (133.694 us; speedup 1.0000x reference)
//
#include <hip/hip_runtime.h>

// Problem: x[2048][32][2] fp32 -> pe[2048][32][512] fp32
//   pe[i,b,2p]   = sin(x[i,b,0] * exp(p * -ln(1e4)/256))
//   pe[i,b,2p+1] = cos(x[i,b,1] * exp(p * -ln(1e4)/256))
//
// Write-BW-bound: 128 MiB out, 0.5 MiB in. Harness poison fill (512 MiB,
// ~82us @6.5TB/s) dominates dur_us; kernel floor at fill-speed ~21us.
//
// R2 lesson (prev session): nontemporal stores tanked write BW (~0.9 TB/s).
// This round: batched load/compute/store phases (8 rows/thread) + raw
// v_sin_f32/v_cos_f32 with 1/2pi folded into div_term (1 mul + 1 trans per
// element instead of mul+fract+sin).

#define NUM_ROWS        (2048 * 32)     // (i,b) pairs
#define V4_PER_ROW      (512 / 4)       // 128 float4 per row
#define ROWS_PER_BLOCK  16
#define ROWS_PER_THREAD (ROWS_PER_BLOCK / 2)   // 8; r=0/1 halves the row set

typedef float fvec4 __attribute__((ext_vector_type(4)));

__global__ __launch_bounds__(256) void pe2d_kernel(const float* __restrict__ x,
                                                   float* __restrict__ out) {
    const int tid  = threadIdx.x;
    const int t    = tid & 127;            // float4 index within a row
    const int r    = tid >> 7;             // 0/1: which row of an even/odd pair
    const int row0 = blockIdx.x * ROWS_PER_BLOCK + r;

    // div_term for this thread's channel pair, with 1/(2pi) folded in so the
    // hardware v_sin/v_cos (revolution-input) needs no further scaling.
    const int   p0     = t * 2;
    const float k      = -0.051905126482615036f;   // -log2(10000)/256
    const float inv2pi = 0.15915493667125702f;     // 1/(2*pi)
    const float d0 = exp2f(k * (float)p0)       * inv2pi;
    const float d1 = exp2f(k * (float)(p0 + 1)) * inv2pi;

    const float2* __restrict__ xv = (const float2*)x;

    // Phase 1: issue all 8 broadcast coord loads back-to-back (vmcnt overlap).
    float2 xy[ROWS_PER_THREAD];
    #pragma unroll
    for (int j = 0; j < ROWS_PER_THREAD; ++j)
        xy[j] = xv[row0 + 2 * j];

    // Phase 2: pure VALU — 32 muls + 32 quarter-rate trans per thread.
    // |xy*d| <= 1/(2pi) < 1 revolution: v_sin/v_cos exact-range, no fract.
    fvec4 o[ROWS_PER_THREAD];
    #pragma unroll
    for (int j = 0; j < ROWS_PER_THREAD; ++j) {
        o[j].x = __builtin_amdgcn_sinf(xy[j].x * d0);
        o[j].y = __builtin_amdgcn_cosf(xy[j].y * d0);
        o[j].z = __builtin_amdgcn_sinf(xy[j].x * d1);
        o[j].w = __builtin_amdgcn_cosf(xy[j].y * d1);
    }

    // Phase 3: 8 back-to-back dwordx4 stores, each wave writes contiguous 1KB.
    fvec4* __restrict__ ov = (fvec4*)out + (size_t)row0 * V4_PER_ROW + t;
    #pragma unroll
    for (int j = 0; j < ROWS_PER_THREAD; ++j)
        ov[(size_t)(2 * j) * V4_PER_ROW] = o[j];
}

extern "C" void kernel_launch(void* const* d_in, const int* in_sizes, int n_in,
                              void* d_out, int out_size, void* d_ws, size_t ws_size,
                              hipStream_t stream) {
    const float* x = (const float*)d_in[0];
    float* out = (float*)d_out;
    const int blocks = NUM_ROWS / ROWS_PER_BLOCK;   // 4096
    pe2d_kernel<<<blocks, 256, 0, stream>>>(x, out);
}